// Round 14
// baseline (446.829 us; speedup 1.0000x reference)
//
#include <hip/hip_runtime.h>

#define N_NODES 100000
#define N_EDGES 1600000
#define EMB 128
#define BM 16
#define NSLAB 64
#define BN_EPS 1e-5f

#define SCAN_BLK 512
#define NB_SCAN ((N_NODES + SCAN_BLK - 1) / SCAN_BLK)   // 196
#define NPAD (NB_SCAN * SCAN_BLK)                       // 100352

typedef short short8 __attribute__((ext_vector_type(8)));
typedef float floatx4 __attribute__((ext_vector_type(4)));

__device__ __forceinline__ ushort f2bf(float x) {
    unsigned u = __float_as_uint(x);
    u += 0x7fffu + ((u >> 16) & 1u);   // RNE
    return (ushort)(u >> 16);
}
__device__ __forceinline__ float lo2f(unsigned p) {    // low bf16 of packed u32
    return __uint_as_float(p << 16);
}
__device__ __forceinline__ float hi2f(unsigned p) {    // high bf16 of packed u32
    return __uint_as_float(p & 0xffff0000u);
}

// DPP-based full-wave sum on the VALU pipe (no ds_bpermute):
#define DPP_ADD(x, ctrl, mask) \
    ((x) + __int_as_float(__builtin_amdgcn_update_dpp(0, __float_as_int(x), ctrl, mask, 0xf, true)))

__device__ __forceinline__ float wave_sum63(float x) {
    x = DPP_ADD(x, 0x111, 0xf);   // row_shr:1
    x = DPP_ADD(x, 0x112, 0xf);   // row_shr:2
    x = DPP_ADD(x, 0x114, 0xf);   // row_shr:4
    x = DPP_ADD(x, 0x118, 0xf);   // row_shr:8
    x = DPP_ADD(x, 0x142, 0xa);   // row_bcast15 -> rows 1,3
    x = DPP_ADD(x, 0x143, 0xc);   // row_bcast31 -> rows 2,3
    return __int_as_float(__builtin_amdgcn_readlane(__float_as_int(x), 63));
}

// =================== setup: nf->bf16 + dst histogram + weight frags =========
__global__ __launch_bounds__(256) void setup_kernel(
    const float* __restrict__ nf, ushort* __restrict__ nfbf,
    const int* __restrict__ dst, int* __restrict__ counts,
    const float* __restrict__ W1, const float* __restrict__ W2,
    ushort* __restrict__ w1f, ushort* __restrict__ w2f)
{
    int gtid = blockIdx.x * 256 + threadIdx.x;
    long gstride = (long)gridDim.x * 256;

    if (gtid < 65536) {
        int idx = gtid;
        int i = idx & 7;
        int lane = (idx >> 3) & 63;
        int kloc = ((lane >> 4) << 3) + i;
        int nloc = lane & 15;
        if (idx < 32768) {
            int ks = (idx >> 9) & 3, nt = idx >> 11;
            w1f[idx] = f2bf(W1[(ks * 32 + kloc) * 256 + nt * 16 + nloc]);
        } else {
            int j = idx - 32768;
            int ks = (j >> 9) & 7, nt = j >> 12;
            w2f[j] = f2bf(W2[(ks * 32 + kloc) * 128 + nt * 16 + nloc]);
        }
    }

    long total = (long)N_NODES * EMB / 4;
    for (long p = gtid; p < total; p += gstride) {
        float4 v = ((const float4*)nf)[p];
        ushort4 o;
        o.x = f2bf(v.x); o.y = f2bf(v.y); o.z = f2bf(v.z); o.w = f2bf(v.w);
        ((ushort4*)nfbf)[p] = o;
    }

    for (long e = gtid; e < N_EDGES; e += gstride)
        atomicAdd(&counts[dst[e]], 1);
}

// =================== scan machinery (2 kernels) ===================
__global__ __launch_bounds__(SCAN_BLK) void scan_blocksum_kernel(
    const int* __restrict__ counts, int* __restrict__ blockSums)
{
    __shared__ int red[SCAN_BLK];
    int t = threadIdx.x;
    int i = blockIdx.x * SCAN_BLK + t;
    red[t] = (i < N_NODES) ? counts[i] : 0;
    __syncthreads();
    for (int s = SCAN_BLK / 2; s > 0; s >>= 1) {
        if (t < s) red[t] += red[t + s];
        __syncthreads();
    }
    if (t == 0) blockSums[blockIdx.x] = red[0];
}

__global__ __launch_bounds__(SCAN_BLK) void scan_final_kernel(
    const int* __restrict__ counts, const int* __restrict__ blockSums,
    int* __restrict__ offsets, int* __restrict__ cursor)
{
    __shared__ int s[SCAN_BLK];
    __shared__ int bs[256];
    int t = threadIdx.x;
    if (t < 256) bs[t] = (t < NB_SCAN) ? blockSums[t] : 0;
    __syncthreads();
    for (int off = 1; off < 256; off <<= 1) {
        int v = (t < 256 && t >= off) ? bs[t - off] : 0;
        __syncthreads();
        if (t < 256) bs[t] += v;
        __syncthreads();
    }
    int blockBase = (blockIdx.x == 0) ? 0 : bs[blockIdx.x - 1];

    int i = blockIdx.x * SCAN_BLK + t;
    int orig = (i < N_NODES) ? counts[i] : 0;
    s[t] = orig;
    __syncthreads();
    for (int off = 1; off < SCAN_BLK; off <<= 1) {
        int v = (t >= off) ? s[t - off] : 0;
        __syncthreads();
        s[t] += v;
        __syncthreads();
    }
    int excl = s[t] - orig + blockBase;
    if (i < N_NODES) { offsets[i] = excl; cursor[i] = excl; }
    if (i == N_NODES) offsets[N_NODES] = N_EDGES;
}

// ======== scatter stage A: perm[pos] = e (4B scattered, L2-resident) ========
__global__ __launch_bounds__(256) void scatter_perm_kernel(
    const int* __restrict__ dst, int* __restrict__ cursor, int* __restrict__ perm)
{
    int e = blockIdx.x * 256 + threadIdx.x;
    if (e >= N_EDGES) return;
    int pos = atomicAdd(&cursor[dst[e]], 1);
    perm[pos] = e;
}

// ======== scatter stage B: coalesced record build (random L3 reads) ========
__global__ __launch_bounds__(256) void build_rec_kernel(
    const int* __restrict__ perm, const int* __restrict__ src,
    const float* __restrict__ ef0, const float* __restrict__ ef1,
    int* __restrict__ rec)
{
    int pos = blockIdx.x * 256 + threadIdx.x;
    if (pos >= N_EDGES) return;
    long e = perm[pos];

    const float2* p0 = (const float2*)(ef0 + e * 6);
    float2 q0 = p0[0], q1 = p0[1], q2 = p0[2];
    const float* p1 = ef1 + e * 3;
    float g0 = p1[0], g1 = p1[1], g2 = p1[2];

    int u0 = (int)((unsigned)f2bf(q0.x) | ((unsigned)f2bf(q0.y) << 16));
    int u1 = (int)((unsigned)f2bf(q1.x) | ((unsigned)f2bf(q1.y) << 16));
    int u2 = (int)((unsigned)f2bf(q2.x) | ((unsigned)f2bf(q2.y) << 16));
    int u3 = (int)((unsigned)f2bf(g0)   | ((unsigned)f2bf(g1) << 16));
    int u4 = (int)((unsigned)f2bf(g2));

    int2* out = (int2*)(rec + (long)pos * 6);
    out[0] = make_int2(src[e], u0);
    out[1] = make_int2(u1, u2);
    out[2] = make_int2(u3, u4);
}

// ======== middle-tier scatter: direct 24B records (R12 path) ========
__global__ __launch_bounds__(256) void scatter24_kernel(
    const int* __restrict__ src, const int* __restrict__ dst,
    const float* __restrict__ ef0, const float* __restrict__ ef1,
    int* __restrict__ cursor, int* __restrict__ rec)
{
    int e = blockIdx.x * 256 + threadIdx.x;
    if (e >= N_EDGES) return;
    int t = dst[e];
    int pos = atomicAdd(&cursor[t], 1);

    const float2* p0 = (const float2*)(ef0 + (long)e * 6);
    float2 q0 = p0[0], q1 = p0[1], q2 = p0[2];
    const float* p1 = ef1 + (long)e * 3;
    float g0 = p1[0], g1 = p1[1], g2 = p1[2];

    int u0 = (int)((unsigned)f2bf(q0.x) | ((unsigned)f2bf(q0.y) << 16));
    int u1 = (int)((unsigned)f2bf(q1.x) | ((unsigned)f2bf(q1.y) << 16));
    int u2 = (int)((unsigned)f2bf(q2.x) | ((unsigned)f2bf(q2.y) << 16));
    int u3 = (int)((unsigned)f2bf(g0)   | ((unsigned)f2bf(g1) << 16));
    int u4 = (int)((unsigned)f2bf(g2));

    int2* out = (int2*)(rec + (long)pos * 6);
    out[0] = make_int2(src[e], u0);
    out[1] = make_int2(u1, u2);
    out[2] = make_int2(u3, u4);
}

// per-record read: returns src id, accumulates 9 features (24B records)
__device__ __forceinline__ int read_rec(const int* __restrict__ rec, long pos,
                                        float* fs) {
    const int* p = rec + pos * 6;
    int2 a = ((const int2*)p)[0], b = ((const int2*)p)[1], c = ((const int2*)p)[2];
    unsigned w1 = (unsigned)a.y, w2 = (unsigned)b.x, w3 = (unsigned)b.y;
    unsigned w4 = (unsigned)c.x, w5 = (unsigned)c.y;
    fs[0] += lo2f(w1); fs[1] += hi2f(w1);
    fs[2] += lo2f(w2); fs[3] += hi2f(w2);
    fs[4] += lo2f(w3); fs[5] += hi2f(w3);
    fs[6] += lo2f(w4); fs[7] += hi2f(w4);
    fs[8] += lo2f(w5);
    return a.x;
}

// full-chunk helper (deg >= 64 segments)
__device__ __forceinline__ void gather_full_chunks(
    int& base, int end, int lane, int q, int lp,
    const int* __restrict__ rec, const int4* __restrict__ nf16,
    float4& accA, float4& accB, float* fs)
{
    for (; base + 64 <= end; base += 64) {
        int sid = read_rec(rec, (long)(base + lane), fs);
#pragma unroll 4
        for (int j = 0; j < 16; ++j) {
            int s = __shfl(sid, 4 * j + q);
            int4 nv = nf16[(long)s * 16 + lp];
            accA.x += lo2f((unsigned)nv.x); accA.y += hi2f((unsigned)nv.x);
            accA.z += lo2f((unsigned)nv.y); accA.w += hi2f((unsigned)nv.y);
            accB.x += lo2f((unsigned)nv.z); accB.y += hi2f((unsigned)nv.z);
            accB.z += lo2f((unsigned)nv.w); accB.w += hi2f((unsigned)nv.w);
        }
    }
}

// =================== gather: 2 nodes/wave, 8 rows in flight, bf16 agg out ===
__global__ __launch_bounds__(256, 8) void gather_kernel(
    const ushort* __restrict__ nfbf, const int* __restrict__ rec,
    const int* __restrict__ offsets,
    const float* __restrict__ We0, const float* __restrict__ be0,
    const float* __restrict__ We1, const float* __restrict__ be1,
    ushort* __restrict__ aggbf)
{
    int wv = threadIdx.x >> 6, lane = threadIdx.x & 63;
    int n0 = blockIdx.x * 8 + wv * 2;          // N_NODES % 8 == 0
    int q = lane >> 4, lp = lane & 15;
    const int4* nf16 = (const int4*)nfbf;      // row = 16 int4

    int beg0 = offsets[n0];
    int mid  = offsets[n0 + 1];
    int end1 = offsets[n0 + 2];

    float4 a0A = make_float4(0.f, 0.f, 0.f, 0.f), a0B = a0A;
    float4 a1A = a0A, a1B = a0A;
    float fs0[9] = {}, fs1[9] = {};

    int b0 = beg0, b1 = mid;
    gather_full_chunks(b0, mid, lane, q, lp, rec, nf16, a0A, a0B, fs0);
    gather_full_chunks(b1, end1, lane, q, lp, rec, nf16, a1A, a1B, fs1);

    // interleaved tails
    int m0 = mid - b0, m1 = end1 - b1;
    int sid0 = 0, sid1 = 0;
    if (lane < m0) sid0 = read_rec(rec, (long)(b0 + lane), fs0);
    if (lane < m1) sid1 = read_rec(rec, (long)(b1 + lane), fs1);

    int mx = m0 > m1 ? m0 : m1;
    int rounds = (mx + 3) >> 2;
#pragma unroll 4
    for (int j = 0; j < rounds; ++j) {
        int r = 4 * j + q;
        int s0 = __shfl(sid0, r);
        int s1 = __shfl(sid1, r);
        if (r < m0) {
            int4 nv = nf16[(long)s0 * 16 + lp];
            a0A.x += lo2f((unsigned)nv.x); a0A.y += hi2f((unsigned)nv.x);
            a0A.z += lo2f((unsigned)nv.y); a0A.w += hi2f((unsigned)nv.y);
            a0B.x += lo2f((unsigned)nv.z); a0B.y += hi2f((unsigned)nv.z);
            a0B.z += lo2f((unsigned)nv.w); a0B.w += hi2f((unsigned)nv.w);
        }
        if (r < m1) {
            int4 nv = nf16[(long)s1 * 16 + lp];
            a1A.x += lo2f((unsigned)nv.x); a1A.y += hi2f((unsigned)nv.x);
            a1A.z += lo2f((unsigned)nv.y); a1A.w += hi2f((unsigned)nv.y);
            a1B.x += lo2f((unsigned)nv.z); a1B.y += hi2f((unsigned)nv.z);
            a1B.z += lo2f((unsigned)nv.w); a1B.w += hi2f((unsigned)nv.w);
        }
    }

    // cross-quarter reductions -> values uniform across quarters at fixed lp
#define QRED(v) v += __shfl_xor(v, 16); v += __shfl_xor(v, 32);
    QRED(a0A.x) QRED(a0A.y) QRED(a0A.z) QRED(a0A.w)
    QRED(a0B.x) QRED(a0B.y) QRED(a0B.z) QRED(a0B.w)
    QRED(a1A.x) QRED(a1A.y) QRED(a1A.z) QRED(a1A.w)
    QRED(a1B.x) QRED(a1B.y) QRED(a1B.z) QRED(a1B.w)
#undef QRED

    // feature sums on the VALU pipe
    float fk0[9], fk1[9];
#pragma unroll
    for (int k = 0; k < 9; ++k) {
        fk0[k] = wave_sum63(fs0[k]);
        fk1[k] = wave_sum63(fs1[k]);
    }

    // epilogue over all 4 quarters: node = q&1, dim-half = q>>1
    int nodesel = q & 1;
    int hh = q >> 1;
    long myn = (long)n0 + nodesel;
    float deg = nodesel ? (float)(end1 - mid) : (float)(mid - beg0);
    float4 acc;
    {
        float4 selA, selB;
        selA.x = nodesel ? a1A.x : a0A.x; selA.y = nodesel ? a1A.y : a0A.y;
        selA.z = nodesel ? a1A.z : a0A.z; selA.w = nodesel ? a1A.w : a0A.w;
        selB.x = nodesel ? a1B.x : a0B.x; selB.y = nodesel ? a1B.y : a0B.y;
        selB.z = nodesel ? a1B.z : a0B.z; selB.w = nodesel ? a1B.w : a0B.w;
        acc.x = hh ? selB.x : selA.x; acc.y = hh ? selB.y : selA.y;
        acc.z = hh ? selB.z : selA.z; acc.w = hh ? selB.w : selA.w;
    }
    int fidx = 2 * lp + hh;
    float4 bb0 = ((const float4*)be0)[fidx];
    float4 bb1 = ((const float4*)be1)[fidx];
    float4 e;
    e.x = deg * (bb0.x + bb1.x); e.y = deg * (bb0.y + bb1.y);
    e.z = deg * (bb0.z + bb1.z); e.w = deg * (bb0.w + bb1.w);
#pragma unroll
    for (int k = 0; k < 6; ++k) {
        float f = nodesel ? fk1[k] : fk0[k];
        float4 w = ((const float4*)We0)[k * 32 + fidx];
        e.x = fmaf(f, w.x, e.x); e.y = fmaf(f, w.y, e.y);
        e.z = fmaf(f, w.z, e.z); e.w = fmaf(f, w.w, e.w);
    }
#pragma unroll
    for (int k = 0; k < 3; ++k) {
        float f = nodesel ? fk1[6 + k] : fk0[6 + k];
        float4 w = ((const float4*)We1)[k * 32 + fidx];
        e.x = fmaf(f, w.x, e.x); e.y = fmaf(f, w.y, e.y);
        e.z = fmaf(f, w.z, e.z); e.w = fmaf(f, w.w, e.w);
    }
    ushort4 o;
    o.x = f2bf(acc.x + e.x); o.y = f2bf(acc.y + e.y);
    o.z = f2bf(acc.z + e.z); o.w = f2bf(acc.w + e.w);
    ((ushort4*)aggbf)[myn * 32 + fidx] = o;
}

// =================== LAST resort: atomic path ===================
__global__ __launch_bounds__(256) void edge_scatter_kernel(
    const float* __restrict__ node_feats,
    const float* __restrict__ ef0,
    const float* __restrict__ ef1,
    const int* __restrict__ src,
    const int* __restrict__ dst,
    const float* __restrict__ We0, const float* __restrict__ be0,
    const float* __restrict__ We1, const float* __restrict__ be1,
    float* __restrict__ agg)
{
    __shared__ float wS[10 * EMB];
    int tid = threadIdx.x;
    for (int i = tid; i < 6 * EMB; i += 256) wS[i] = We0[i];
    for (int i = tid; i < 3 * EMB; i += 256) wS[6 * EMB + i] = We1[i];
    if (tid < EMB) wS[9 * EMB + tid] = be0[tid] + be1[tid];
    __syncthreads();

    int e = blockIdx.x * 2 + (tid >> 7);
    if (e >= N_EDGES) return;
    int d = tid & 127;
    int s = src[e];
    int t = dst[e];
    const float* f0 = ef0 + (long)e * 6;
    const float* f1 = ef1 + (long)e * 3;

    float emb = wS[9 * EMB + d];
#pragma unroll
    for (int k = 0; k < 6; ++k) emb = fmaf(f0[k], wS[k * EMB + d], emb);
#pragma unroll
    for (int k = 0; k < 3; ++k) emb = fmaf(f1[k], wS[6 * EMB + k * EMB + d], emb);

    float val = node_feats[(long)s * EMB + d] + emb;
    atomicAdd(&agg[(long)t * EMB + d], val);
}

// =============== fused MFMA MLP + BN stats (A bf16 in, h bf16 out) ==========
__global__ __launch_bounds__(256) void mlp_mfma_kernel(
    const ushort* __restrict__ aggbf, ushort* __restrict__ hbf,
    const ushort* __restrict__ w1f, const ushort* __restrict__ w2f,
    const float* __restrict__ b1, const float* __restrict__ b2,
    float* __restrict__ stats)
{
    __shared__ __align__(16) char h1S[32 * 512];    // 32 rows x 256 bf16, swizzled

    int tid = threadIdx.x;
    int lane = tid & 63;
    int wv = tid >> 6;
    long base = (long)blockIdx.x * 32;

    // ---- A fragments straight from global bf16 agg ----
    short8 a[2][4];
#pragma unroll
    for (int mt = 0; mt < 2; ++mt)
#pragma unroll
        for (int ks = 0; ks < 4; ++ks) {
            long row = base + mt * 16 + (lane & 15);
            a[mt][ks] = *(const short8*)&aggbf[row * EMB + ks * 32 + ((lane >> 4) << 3)];
        }

    // ---- GEMM1: wave wv owns n-tiles [wv*4, wv*4+4) ----
    floatx4 acc1[2][4];
#pragma unroll
    for (int nt = 0; nt < 4; ++nt) {
        float bias = b1[(wv * 4 + nt) * 16 + (lane & 15)];
#pragma unroll
        for (int mt = 0; mt < 2; ++mt)
            acc1[mt][nt] = (floatx4){bias, bias, bias, bias};
    }
#pragma unroll
    for (int ks = 0; ks < 4; ++ks) {
#pragma unroll
        for (int nt = 0; nt < 4; ++nt) {
            short8 b = *(const short8*)&w1f[(((wv * 4 + nt) * 4 + ks) * 64 + lane) * 8];
            acc1[0][nt] = __builtin_amdgcn_mfma_f32_16x16x32_bf16(a[0][ks], b, acc1[0][nt], 0, 0, 0);
            acc1[1][nt] = __builtin_amdgcn_mfma_f32_16x16x32_bf16(a[1][ks], b, acc1[1][nt], 0, 0, 0);
        }
    }
    // relu -> bf16 -> h1S (swizzled)
#pragma unroll
    for (int mt = 0; mt < 2; ++mt)
#pragma unroll
        for (int nt = 0; nt < 4; ++nt)
#pragma unroll
            for (int i = 0; i < 4; ++i) {
                int row = mt * 16 + ((lane >> 4) << 2) + i;
                int col = (wv * 4 + nt) * 16 + (lane & 15);
                float v = fmaxf(acc1[mt][nt][i], 0.f);
                *(ushort*)&h1S[row * 512 + ((2 * col) ^ ((row & 7) << 4))] = f2bf(v);
            }
    __syncthreads();

    // ---- GEMM2: wave wv owns n-tiles [wv*2, wv*2+2) ----
    int swz = (lane & 7) << 4;
    floatx4 acc2[2][2];
#pragma unroll
    for (int nt = 0; nt < 2; ++nt) {
        float bias = b2[(wv * 2 + nt) * 16 + (lane & 15)];
#pragma unroll
        for (int mt = 0; mt < 2; ++mt)
            acc2[mt][nt] = (floatx4){bias, bias, bias, bias};
    }
#pragma unroll
    for (int ks = 0; ks < 8; ++ks) {
        int kb = ks * 64 + ((lane >> 4) << 4);
        short8 a0 = *(const short8*)&h1S[(lane & 15) * 512 + (kb ^ swz)];
        short8 a1 = *(const short8*)&h1S[(16 + (lane & 15)) * 512 + (kb ^ swz)];
#pragma unroll
        for (int nt = 0; nt < 2; ++nt) {
            short8 b = *(const short8*)&w2f[(((wv * 2 + nt) * 8 + ks) * 64 + lane) * 8];
            acc2[0][nt] = __builtin_amdgcn_mfma_f32_16x16x32_bf16(a0, b, acc2[0][nt], 0, 0, 0);
            acc2[1][nt] = __builtin_amdgcn_mfma_f32_16x16x32_bf16(a1, b, acc2[1][nt], 0, 0, 0);
        }
    }

    // ---- epilogue: bf16 store + per-column stats (fp32 pre-rounding) ----
    float s[2] = {0.f, 0.f}, s2[2] = {0.f, 0.f};
#pragma unroll
    for (int nt = 0; nt < 2; ++nt) {
        int col = (wv * 2 + nt) * 16 + (lane & 15);
#pragma unroll
        for (int mt = 0; mt < 2; ++mt)
#pragma unroll
            for (int i = 0; i < 4; ++i) {
                int row = mt * 16 + ((lane >> 4) << 2) + i;
                float v = acc2[mt][nt][i];
                hbf[(base + row) * EMB + col] = f2bf(v);
                s[nt] += v;
                s2[nt] = fmaf(v, v, s2[nt]);
            }
    }
#pragma unroll
    for (int nt = 0; nt < 2; ++nt) {
        s[nt] += __shfl_xor(s[nt], 16);
        s[nt] += __shfl_xor(s[nt], 32);
        s2[nt] += __shfl_xor(s2[nt], 16);
        s2[nt] += __shfl_xor(s2[nt], 32);
    }
    if (lane < 16) {
        float* slab = stats + (blockIdx.x & (NSLAB - 1)) * (2 * EMB);
#pragma unroll
        for (int nt = 0; nt < 2; ++nt) {
            int col = (wv * 2 + nt) * 16 + lane;
            atomicAdd(&slab[col], s[nt]);
            atomicAdd(&slab[EMB + col], s2[nt]);
        }
    }
}

// =================== fp32 MLP fallback (atomic tier only) ===================
__global__ __launch_bounds__(256) void mlp_kernel(
    float* __restrict__ h,
    const float* __restrict__ W1, const float* __restrict__ b1,
    const float* __restrict__ W2, const float* __restrict__ b2,
    float* __restrict__ stats)
{
    __shared__ float aggS[BM][EMB];
    __shared__ float h1S[BM][2 * EMB];
    __shared__ float sredS[256];
    __shared__ float s2redS[256];

    int tid = threadIdx.x;
    long base = (long)blockIdx.x * BM;

    for (int i = tid; i < BM * EMB; i += 256)
        aggS[i >> 7][i & 127] = h[base * EMB + i];
    __syncthreads();

    {
        float acc[BM];
        float bias = b1[tid];
#pragma unroll
        for (int r = 0; r < BM; ++r) acc[r] = bias;
        for (int k = 0; k < EMB; ++k) {
            float w = W1[k * (2 * EMB) + tid];
#pragma unroll
            for (int r = 0; r < BM; ++r) acc[r] = fmaf(aggS[r][k], w, acc[r]);
        }
#pragma unroll
        for (int r = 0; r < BM; ++r) h1S[r][tid] = fmaxf(acc[r], 0.0f);
    }
    __syncthreads();

    {
        int c = tid & 127;
        int half = tid >> 7;
        float acc[8];
        float bias = b2[c];
#pragma unroll
        for (int r = 0; r < 8; ++r) acc[r] = bias;
        for (int k = 0; k < 2 * EMB; ++k) {
            float w = W2[k * EMB + c];
#pragma unroll
            for (int r = 0; r < 8; ++r) acc[r] = fmaf(h1S[half * 8 + r][k], w, acc[r]);
        }
        float s = 0.f, s2 = 0.f;
#pragma unroll
        for (int r = 0; r < 8; ++r) {
            h[(base + half * 8 + r) * EMB + c] = acc[r];
            s += acc[r];
            s2 = fmaf(acc[r], acc[r], s2);
        }
        sredS[tid] = s;
        s2redS[tid] = s2;
    }
    __syncthreads();
    if (tid < 128) {
        float s = sredS[tid] + sredS[tid + 128];
        float s2 = s2redS[tid] + s2redS[tid + 128];
        float* slab = stats + (blockIdx.x & (NSLAB - 1)) * (2 * EMB);
        atomicAdd(&slab[tid], s);
        atomicAdd(&slab[EMB + tid], s2);
    }
}

// =================== BN apply: bf16 h in -> fp32 out ===============
__global__ __launch_bounds__(256) void bn_apply_bf16_kernel(
    const ushort* __restrict__ hbf, float* __restrict__ out,
    const float* __restrict__ stats,
    const float* __restrict__ gamma, const float* __restrict__ beta)
{
    __shared__ float scS[EMB], shS[EMB];
    int tid = threadIdx.x;
    if (tid < EMB) {
        float s = 0.f, s2 = 0.f;
        for (int b = 0; b < NSLAB; ++b) {
            s += stats[b * (2 * EMB) + tid];
            s2 += stats[b * (2 * EMB) + EMB + tid];
        }
        float mean = s / (float)N_NODES;
        float var = s2 / (float)N_NODES - mean * mean;
        float sc = gamma[tid] * rsqrtf(var + BN_EPS);
        scS[tid] = sc;
        shS[tid] = beta[tid] - mean * sc;
    }
    __syncthreads();
    long total = (long)N_NODES * EMB / 8;           // uint4 = 8 bf16
    long stride = (long)gridDim.x * blockDim.x;
    for (long p = (long)blockIdx.x * blockDim.x + threadIdx.x; p < total; p += stride) {
        uint4 v = ((const uint4*)hbf)[p];
        int c = (int)((p * 8) & 127);
        float4 o1, o2;
        o1.x = fmaf(lo2f(v.x), scS[c + 0], shS[c + 0]);
        o1.y = fmaf(hi2f(v.x), scS[c + 1], shS[c + 1]);
        o1.z = fmaf(lo2f(v.y), scS[c + 2], shS[c + 2]);
        o1.w = fmaf(hi2f(v.y), scS[c + 3], shS[c + 3]);
        o2.x = fmaf(lo2f(v.z), scS[c + 4], shS[c + 4]);
        o2.y = fmaf(hi2f(v.z), scS[c + 5], shS[c + 5]);
        o2.z = fmaf(lo2f(v.w), scS[c + 6], shS[c + 6]);
        o2.w = fmaf(hi2f(v.w), scS[c + 7], shS[c + 7]);
        ((float4*)out)[2 * p] = o1;
        ((float4*)out)[2 * p + 1] = o2;
    }
}

// =================== BN apply fp32 in-place (fallback tier) ===============
__global__ __launch_bounds__(256) void bn_apply_fused_kernel(
    float* __restrict__ h, const float* __restrict__ stats,
    const float* __restrict__ gamma, const float* __restrict__ beta)
{
    __shared__ float scS[EMB], shS[EMB];
    int tid = threadIdx.x;
    if (tid < EMB) {
        float s = 0.f, s2 = 0.f;
        for (int b = 0; b < NSLAB; ++b) {
            s += stats[b * (2 * EMB) + tid];
            s2 += stats[b * (2 * EMB) + EMB + tid];
        }
        float mean = s / (float)N_NODES;
        float var = s2 / (float)N_NODES - mean * mean;
        float sc = gamma[tid] * rsqrtf(var + BN_EPS);
        scS[tid] = sc;
        shS[tid] = beta[tid] - mean * sc;
    }
    __syncthreads();
    long total = (long)N_NODES * EMB / 4;
    long stride = (long)gridDim.x * blockDim.x;
    for (long i = (long)blockIdx.x * blockDim.x + threadIdx.x; i < total; i += stride) {
        float4 v = ((float4*)h)[i];
        int c = (int)((i * 4) & 127);
        v.x = fmaf(v.x, scS[c + 0], shS[c + 0]);
        v.y = fmaf(v.y, scS[c + 1], shS[c + 1]);
        v.z = fmaf(v.z, scS[c + 2], shS[c + 2]);
        v.w = fmaf(v.w, scS[c + 3], shS[c + 3]);
        ((float4*)h)[i] = v;
    }
}

extern "C" void kernel_launch(void* const* d_in, const int* in_sizes, int n_in,
                              void* d_out, int out_size, void* d_ws, size_t ws_size,
                              hipStream_t stream) {
    const float* node_feats = (const float*)d_in[0];
    const float* ef0 = (const float*)d_in[1];
    const float* ef1 = (const float*)d_in[2];
    const int* src = (const int*)d_in[3];
    const int* dst = (const int*)d_in[4];
    const float* We0 = (const float*)d_in[5];
    const float* be0 = (const float*)d_in[6];
    const float* We1 = (const float*)d_in[7];
    const float* be1 = (const float*)d_in[8];
    const float* W1 = (const float*)d_in[9];
    const float* b1 = (const float*)d_in[10];
    const float* W2 = (const float*)d_in[11];
    const float* b2 = (const float*)d_in[12];
    const float* gamma = (const float*)d_in[13];
    const float* beta = (const float*)d_in[14];

    float* out = (float*)d_out;
    ushort* aggbf = (ushort*)d_out;   // bf16 agg lives in d_out's first half

    // ws layout
    float* stats = (float*)d_ws;                          // 65536 B
    float* scaleshift = stats + NSLAB * 2 * EMB;          // 1024 B (pad)
    int* counts = (int*)(scaleshift + 256);               // NPAD ints
    int* offsets = counts + NPAD;                         // NPAD ints
    int* cursor = offsets + NPAD;                         // NPAD ints
    int* blockSums = cursor + NPAD;                       // 1024 B
    ushort* w1f = (ushort*)(blockSums + 256);             // 64 KB
    ushort* w2f = w1f + 32768;                            // 64 KB
    int* perm = (int*)(w2f + 32768);                      // E ints (6.4 MB)
    int* recA = perm + N_EDGES;                           // E*24B after perm
    ushort* nfbfA = (ushort*)(recA + (size_t)N_EDGES * 6);
    size_t needA = (size_t)((char*)(nfbfA + (size_t)N_NODES * EMB) - (char*)d_ws); // ~71.8MB (< proven 78.1)
    int* recB = (int*)(w2f + 32768);                      // no perm
    ushort* nfbfB = (ushort*)(recB + (size_t)N_EDGES * 6);
    size_t needB = (size_t)((char*)(nfbfB + (size_t)N_NODES * EMB) - (char*)d_ws); // ~65.4MB

    if (ws_size >= needB) {
        bool tierA = (ws_size >= needA);
        int* rec = tierA ? recA : recB;
        ushort* nfbf = tierA ? nfbfA : nfbfB;
        ushort* hbf = (ushort*)rec;                        // reuse after gather

        hipMemsetAsync(d_ws, 0,
            (size_t)(NSLAB * 2 * EMB + 256) * sizeof(float) + (size_t)NPAD * sizeof(int),
            stream);
        setup_kernel<<<2048, 256, 0, stream>>>(
            node_feats, nfbf, dst, counts, W1, W2, w1f, w2f);
        scan_blocksum_kernel<<<NB_SCAN, SCAN_BLK, 0, stream>>>(counts, blockSums);
        scan_final_kernel<<<NB_SCAN, SCAN_BLK, 0, stream>>>(counts, blockSums, offsets, cursor);
        if (tierA) {
            scatter_perm_kernel<<<(N_EDGES + 255) / 256, 256, 0, stream>>>(dst, cursor, perm);
            build_rec_kernel<<<(N_EDGES + 255) / 256, 256, 0, stream>>>(
                perm, src, ef0, ef1, rec);
        } else {
            scatter24_kernel<<<(N_EDGES + 255) / 256, 256, 0, stream>>>(
                src, dst, ef0, ef1, cursor, rec);
        }
        gather_kernel<<<N_NODES / 8, 256, 0, stream>>>(
            nfbf, rec, offsets, We0, be0, We1, be1, aggbf);
        mlp_mfma_kernel<<<N_NODES / 32, 256, 0, stream>>>(
            aggbf, hbf, w1f, w2f, b1, b2, stats);
        bn_apply_bf16_kernel<<<1024, 256, 0, stream>>>(hbf, out, stats, gamma, beta);
    } else {
        hipMemsetAsync(stats, 0, (size_t)NSLAB * 2 * EMB * sizeof(float), stream);
        hipMemsetAsync(d_out, 0, (size_t)N_NODES * EMB * sizeof(float), stream);
        edge_scatter_kernel<<<N_EDGES / 2, 256, 0, stream>>>(
            node_feats, ef0, ef1, src, dst, We0, be0, We1, be1, out);
        mlp_kernel<<<N_NODES / BM, 256, 0, stream>>>(out, W1, b1, W2, b2, stats);
        bn_apply_fused_kernel<<<4096, 256, 0, stream>>>(out, stats, gamma, beta);
    }
}

// Round 15
// 330.588 us; speedup vs baseline: 1.3516x; 1.3516x over previous
//
#include <hip/hip_runtime.h>

#define N_NODES 100000
#define N_EDGES 1600000
#define EMB 128
#define BM 16
#define NSLAB 64
#define BN_EPS 1e-5f

#define SCAN_BLK 512
#define NB_SCAN ((N_NODES + SCAN_BLK - 1) / SCAN_BLK)   // 196
#define NPAD (NB_SCAN * SCAN_BLK)                       // 100352

typedef short short8 __attribute__((ext_vector_type(8)));
typedef float floatx4 __attribute__((ext_vector_type(4)));

__device__ __forceinline__ ushort f2bf(float x) {
    unsigned u = __float_as_uint(x);
    u += 0x7fffu + ((u >> 16) & 1u);   // RNE
    return (ushort)(u >> 16);
}
__device__ __forceinline__ float lo2f(unsigned p) {    // low bf16 of packed u32
    return __uint_as_float(p << 16);
}
__device__ __forceinline__ float hi2f(unsigned p) {    // high bf16 of packed u32
    return __uint_as_float(p & 0xffff0000u);
}

// DPP-based full-wave sum on the VALU pipe (no ds_bpermute):
#define DPP_ADD(x, ctrl, mask) \
    ((x) + __int_as_float(__builtin_amdgcn_update_dpp(0, __float_as_int(x), ctrl, mask, 0xf, true)))

__device__ __forceinline__ float wave_sum63(float x) {
    x = DPP_ADD(x, 0x111, 0xf);   // row_shr:1
    x = DPP_ADD(x, 0x112, 0xf);   // row_shr:2
    x = DPP_ADD(x, 0x114, 0xf);   // row_shr:4
    x = DPP_ADD(x, 0x118, 0xf);   // row_shr:8
    x = DPP_ADD(x, 0x142, 0xa);   // row_bcast15 -> rows 1,3
    x = DPP_ADD(x, 0x143, 0xc);   // row_bcast31 -> rows 2,3
    return __int_as_float(__builtin_amdgcn_readlane(__float_as_int(x), 63));
}

// =================== hist: counts[dst[e]]++ ===================
__global__ __launch_bounds__(256) void hist_kernel(
    const int* __restrict__ dst, int* __restrict__ counts)
{
    int e = blockIdx.x * 256 + threadIdx.x;
    if (e < N_EDGES) atomicAdd(&counts[dst[e]], 1);
}

// =================== scan machinery (2 kernels) ===================
__global__ __launch_bounds__(SCAN_BLK) void scan_blocksum_kernel(
    const int* __restrict__ counts, int* __restrict__ blockSums)
{
    __shared__ int red[SCAN_BLK];
    int t = threadIdx.x;
    int i = blockIdx.x * SCAN_BLK + t;
    red[t] = (i < N_NODES) ? counts[i] : 0;
    __syncthreads();
    for (int s = SCAN_BLK / 2; s > 0; s >>= 1) {
        if (t < s) red[t] += red[t + s];
        __syncthreads();
    }
    if (t == 0) blockSums[blockIdx.x] = red[0];
}

__global__ __launch_bounds__(SCAN_BLK) void scan_final_kernel(
    const int* __restrict__ counts, const int* __restrict__ blockSums,
    int* __restrict__ offsets, int* __restrict__ cursor)
{
    __shared__ int s[SCAN_BLK];
    __shared__ int bs[256];
    int t = threadIdx.x;
    if (t < 256) bs[t] = (t < NB_SCAN) ? blockSums[t] : 0;
    __syncthreads();
    for (int off = 1; off < 256; off <<= 1) {
        int v = (t < 256 && t >= off) ? bs[t - off] : 0;
        __syncthreads();
        if (t < 256) bs[t] += v;
        __syncthreads();
    }
    int blockBase = (blockIdx.x == 0) ? 0 : bs[blockIdx.x - 1];

    int i = blockIdx.x * SCAN_BLK + t;
    int orig = (i < N_NODES) ? counts[i] : 0;
    s[t] = orig;
    __syncthreads();
    for (int off = 1; off < SCAN_BLK; off <<= 1) {
        int v = (t >= off) ? s[t - off] : 0;
        __syncthreads();
        s[t] += v;
        __syncthreads();
    }
    int excl = s[t] - orig + blockBase;
    if (i < N_NODES) { offsets[i] = excl; cursor[i] = excl; }
    if (i == N_NODES) offsets[N_NODES] = N_EDGES;
}

// ====== fused: 24B record scatter + nf->bf16 cvt + weight frag prep =========
// Scatter is write-port-bound (VALUBusy ~1.6%), so the coalesced cvt and the
// tiny frag prep ride along on idle read BW / VALU.
__global__ __launch_bounds__(256) void scatter_fused_kernel(
    const int* __restrict__ src, const int* __restrict__ dst,
    const float* __restrict__ ef0, const float* __restrict__ ef1,
    int* __restrict__ cursor, int* __restrict__ rec,
    const float* __restrict__ nf, ushort* __restrict__ nfbf,
    const float* __restrict__ W1, const float* __restrict__ W2,
    ushort* __restrict__ w1f, ushort* __restrict__ w2f)
{
    int gtid = blockIdx.x * 256 + threadIdx.x;
    long gstride = (long)gridDim.x * 256;

    // ---- edge scatter (24B records sorted by dst) ----
    if (gtid < N_EDGES) {
        int e = gtid;
        int t = dst[e];
        int pos = atomicAdd(&cursor[t], 1);

        const float2* p0 = (const float2*)(ef0 + (long)e * 6);
        float2 q0 = p0[0], q1 = p0[1], q2 = p0[2];
        const float* p1 = ef1 + (long)e * 3;
        float g0 = p1[0], g1 = p1[1], g2 = p1[2];

        int u0 = (int)((unsigned)f2bf(q0.x) | ((unsigned)f2bf(q0.y) << 16));
        int u1 = (int)((unsigned)f2bf(q1.x) | ((unsigned)f2bf(q1.y) << 16));
        int u2 = (int)((unsigned)f2bf(q2.x) | ((unsigned)f2bf(q2.y) << 16));
        int u3 = (int)((unsigned)f2bf(g0)   | ((unsigned)f2bf(g1) << 16));
        int u4 = (int)((unsigned)f2bf(g2));

        int2* out = (int2*)(rec + (long)pos * 6);
        out[0] = make_int2(src[e], u0);
        out[1] = make_int2(u1, u2);
        out[2] = make_int2(u3, u4);
    }

    // ---- weight fragments (first 65536 threads) ----
    if (gtid < 65536) {
        int idx = gtid;
        int i = idx & 7;
        int lane = (idx >> 3) & 63;
        int kloc = ((lane >> 4) << 3) + i;
        int nloc = lane & 15;
        if (idx < 32768) {
            int ks = (idx >> 9) & 3, nt = idx >> 11;
            w1f[idx] = f2bf(W1[(ks * 32 + kloc) * 256 + nt * 16 + nloc]);
        } else {
            int j = idx - 32768;
            int ks = (j >> 9) & 7, nt = j >> 12;
            w2f[j] = f2bf(W2[(ks * 32 + kloc) * 128 + nt * 16 + nloc]);
        }
    }

    // ---- node_feats -> bf16 (grid-stride) ----
    long total = (long)N_NODES * EMB / 4;
    for (long p = gtid; p < total; p += gstride) {
        float4 v = ((const float4*)nf)[p];
        ushort4 o;
        o.x = f2bf(v.x); o.y = f2bf(v.y); o.z = f2bf(v.z); o.w = f2bf(v.w);
        ((ushort4*)nfbf)[p] = o;
    }
}

// per-record read: returns src id, accumulates 9 features (24B records)
__device__ __forceinline__ int read_rec(const int* __restrict__ rec, long pos,
                                        float* fs) {
    const int* p = rec + pos * 6;
    int2 a = ((const int2*)p)[0], b = ((const int2*)p)[1], c = ((const int2*)p)[2];
    unsigned w1 = (unsigned)a.y, w2 = (unsigned)b.x, w3 = (unsigned)b.y;
    unsigned w4 = (unsigned)c.x, w5 = (unsigned)c.y;
    fs[0] += lo2f(w1); fs[1] += hi2f(w1);
    fs[2] += lo2f(w2); fs[3] += hi2f(w2);
    fs[4] += lo2f(w3); fs[5] += hi2f(w3);
    fs[6] += lo2f(w4); fs[7] += hi2f(w4);
    fs[8] += lo2f(w5);
    return a.x;
}

// full-chunk helper (deg >= 64 segments)
__device__ __forceinline__ void gather_full_chunks(
    int& base, int end, int lane, int q, int lp,
    const int* __restrict__ rec, const int4* __restrict__ nf16,
    float4& accA, float4& accB, float* fs)
{
    for (; base + 64 <= end; base += 64) {
        int sid = read_rec(rec, (long)(base + lane), fs);
#pragma unroll 4
        for (int j = 0; j < 16; ++j) {
            int s = __shfl(sid, 4 * j + q);
            int4 nv = nf16[(long)s * 16 + lp];
            accA.x += lo2f((unsigned)nv.x); accA.y += hi2f((unsigned)nv.x);
            accA.z += lo2f((unsigned)nv.y); accA.w += hi2f((unsigned)nv.y);
            accB.x += lo2f((unsigned)nv.z); accB.y += hi2f((unsigned)nv.z);
            accB.z += lo2f((unsigned)nv.w); accB.w += hi2f((unsigned)nv.w);
        }
    }
}

// =================== gather: 2 nodes/wave, 8 rows in flight, bf16 agg out ===
__global__ __launch_bounds__(256, 8) void gather_kernel(
    const ushort* __restrict__ nfbf, const int* __restrict__ rec,
    const int* __restrict__ offsets,
    const float* __restrict__ We0, const float* __restrict__ be0,
    const float* __restrict__ We1, const float* __restrict__ be1,
    ushort* __restrict__ aggbf)
{
    int wv = threadIdx.x >> 6, lane = threadIdx.x & 63;
    int n0 = blockIdx.x * 8 + wv * 2;          // N_NODES % 8 == 0
    int q = lane >> 4, lp = lane & 15;
    const int4* nf16 = (const int4*)nfbf;      // row = 16 int4

    int beg0 = offsets[n0];
    int mid  = offsets[n0 + 1];
    int end1 = offsets[n0 + 2];

    float4 a0A = make_float4(0.f, 0.f, 0.f, 0.f), a0B = a0A;
    float4 a1A = a0A, a1B = a0A;
    float fs0[9] = {}, fs1[9] = {};

    int b0 = beg0, b1 = mid;
    gather_full_chunks(b0, mid, lane, q, lp, rec, nf16, a0A, a0B, fs0);
    gather_full_chunks(b1, end1, lane, q, lp, rec, nf16, a1A, a1B, fs1);

    // interleaved tails
    int m0 = mid - b0, m1 = end1 - b1;
    int sid0 = 0, sid1 = 0;
    if (lane < m0) sid0 = read_rec(rec, (long)(b0 + lane), fs0);
    if (lane < m1) sid1 = read_rec(rec, (long)(b1 + lane), fs1);

    int mx = m0 > m1 ? m0 : m1;
    int rounds = (mx + 3) >> 2;
#pragma unroll 4
    for (int j = 0; j < rounds; ++j) {
        int r = 4 * j + q;
        int s0 = __shfl(sid0, r);
        int s1 = __shfl(sid1, r);
        if (r < m0) {
            int4 nv = nf16[(long)s0 * 16 + lp];
            a0A.x += lo2f((unsigned)nv.x); a0A.y += hi2f((unsigned)nv.x);
            a0A.z += lo2f((unsigned)nv.y); a0A.w += hi2f((unsigned)nv.y);
            a0B.x += lo2f((unsigned)nv.z); a0B.y += hi2f((unsigned)nv.z);
            a0B.z += lo2f((unsigned)nv.w); a0B.w += hi2f((unsigned)nv.w);
        }
        if (r < m1) {
            int4 nv = nf16[(long)s1 * 16 + lp];
            a1A.x += lo2f((unsigned)nv.x); a1A.y += hi2f((unsigned)nv.x);
            a1A.z += lo2f((unsigned)nv.y); a1A.w += hi2f((unsigned)nv.y);
            a1B.x += lo2f((unsigned)nv.z); a1B.y += hi2f((unsigned)nv.z);
            a1B.z += lo2f((unsigned)nv.w); a1B.w += hi2f((unsigned)nv.w);
        }
    }

    // cross-quarter reductions -> values uniform across quarters at fixed lp
#define QRED(v) v += __shfl_xor(v, 16); v += __shfl_xor(v, 32);
    QRED(a0A.x) QRED(a0A.y) QRED(a0A.z) QRED(a0A.w)
    QRED(a0B.x) QRED(a0B.y) QRED(a0B.z) QRED(a0B.w)
    QRED(a1A.x) QRED(a1A.y) QRED(a1A.z) QRED(a1A.w)
    QRED(a1B.x) QRED(a1B.y) QRED(a1B.z) QRED(a1B.w)
#undef QRED

    // feature sums on the VALU pipe
    float fk0[9], fk1[9];
#pragma unroll
    for (int k = 0; k < 9; ++k) {
        fk0[k] = wave_sum63(fs0[k]);
        fk1[k] = wave_sum63(fs1[k]);
    }

    // epilogue over all 4 quarters: node = q&1, dim-half = q>>1
    int nodesel = q & 1;
    int hh = q >> 1;
    long myn = (long)n0 + nodesel;
    float deg = nodesel ? (float)(end1 - mid) : (float)(mid - beg0);
    float4 acc;
    {
        float4 selA, selB;
        selA.x = nodesel ? a1A.x : a0A.x; selA.y = nodesel ? a1A.y : a0A.y;
        selA.z = nodesel ? a1A.z : a0A.z; selA.w = nodesel ? a1A.w : a0A.w;
        selB.x = nodesel ? a1B.x : a0B.x; selB.y = nodesel ? a1B.y : a0B.y;
        selB.z = nodesel ? a1B.z : a0B.z; selB.w = nodesel ? a1B.w : a0B.w;
        acc.x = hh ? selB.x : selA.x; acc.y = hh ? selB.y : selA.y;
        acc.z = hh ? selB.z : selA.z; acc.w = hh ? selB.w : selA.w;
    }
    int fidx = 2 * lp + hh;
    float4 bb0 = ((const float4*)be0)[fidx];
    float4 bb1 = ((const float4*)be1)[fidx];
    float4 e;
    e.x = deg * (bb0.x + bb1.x); e.y = deg * (bb0.y + bb1.y);
    e.z = deg * (bb0.z + bb1.z); e.w = deg * (bb0.w + bb1.w);
#pragma unroll
    for (int k = 0; k < 6; ++k) {
        float f = nodesel ? fk1[k] : fk0[k];
        float4 w = ((const float4*)We0)[k * 32 + fidx];
        e.x = fmaf(f, w.x, e.x); e.y = fmaf(f, w.y, e.y);
        e.z = fmaf(f, w.z, e.z); e.w = fmaf(f, w.w, e.w);
    }
#pragma unroll
    for (int k = 0; k < 3; ++k) {
        float f = nodesel ? fk1[6 + k] : fk0[6 + k];
        float4 w = ((const float4*)We1)[k * 32 + fidx];
        e.x = fmaf(f, w.x, e.x); e.y = fmaf(f, w.y, e.y);
        e.z = fmaf(f, w.z, e.z); e.w = fmaf(f, w.w, e.w);
    }
    ushort4 o;
    o.x = f2bf(acc.x + e.x); o.y = f2bf(acc.y + e.y);
    o.z = f2bf(acc.z + e.z); o.w = f2bf(acc.w + e.w);
    ((ushort4*)aggbf)[myn * 32 + fidx] = o;
}

// =================== LAST resort: atomic path ===================
__global__ __launch_bounds__(256) void edge_scatter_kernel(
    const float* __restrict__ node_feats,
    const float* __restrict__ ef0,
    const float* __restrict__ ef1,
    const int* __restrict__ src,
    const int* __restrict__ dst,
    const float* __restrict__ We0, const float* __restrict__ be0,
    const float* __restrict__ We1, const float* __restrict__ be1,
    float* __restrict__ agg)
{
    __shared__ float wS[10 * EMB];
    int tid = threadIdx.x;
    for (int i = tid; i < 6 * EMB; i += 256) wS[i] = We0[i];
    for (int i = tid; i < 3 * EMB; i += 256) wS[6 * EMB + i] = We1[i];
    if (tid < EMB) wS[9 * EMB + tid] = be0[tid] + be1[tid];
    __syncthreads();

    int e = blockIdx.x * 2 + (tid >> 7);
    if (e >= N_EDGES) return;
    int d = tid & 127;
    int s = src[e];
    int t = dst[e];
    const float* f0 = ef0 + (long)e * 6;
    const float* f1 = ef1 + (long)e * 3;

    float emb = wS[9 * EMB + d];
#pragma unroll
    for (int k = 0; k < 6; ++k) emb = fmaf(f0[k], wS[k * EMB + d], emb);
#pragma unroll
    for (int k = 0; k < 3; ++k) emb = fmaf(f1[k], wS[6 * EMB + k * EMB + d], emb);

    float val = node_feats[(long)s * EMB + d] + emb;
    atomicAdd(&agg[(long)t * EMB + d], val);
}

// =============== fused MFMA MLP + BN stats (A bf16 in, h bf16 out) ==========
__global__ __launch_bounds__(256) void mlp_mfma_kernel(
    const ushort* __restrict__ aggbf, ushort* __restrict__ hbf,
    const ushort* __restrict__ w1f, const ushort* __restrict__ w2f,
    const float* __restrict__ b1, const float* __restrict__ b2,
    float* __restrict__ stats)
{
    __shared__ __align__(16) char h1S[32 * 512];    // 32 rows x 256 bf16, swizzled

    int tid = threadIdx.x;
    int lane = tid & 63;
    int wv = tid >> 6;
    long base = (long)blockIdx.x * 32;

    // ---- A fragments straight from global bf16 agg ----
    short8 a[2][4];
#pragma unroll
    for (int mt = 0; mt < 2; ++mt)
#pragma unroll
        for (int ks = 0; ks < 4; ++ks) {
            long row = base + mt * 16 + (lane & 15);
            a[mt][ks] = *(const short8*)&aggbf[row * EMB + ks * 32 + ((lane >> 4) << 3)];
        }

    // ---- GEMM1: wave wv owns n-tiles [wv*4, wv*4+4) ----
    floatx4 acc1[2][4];
#pragma unroll
    for (int nt = 0; nt < 4; ++nt) {
        float bias = b1[(wv * 4 + nt) * 16 + (lane & 15)];
#pragma unroll
        for (int mt = 0; mt < 2; ++mt)
            acc1[mt][nt] = (floatx4){bias, bias, bias, bias};
    }
#pragma unroll
    for (int ks = 0; ks < 4; ++ks) {
#pragma unroll
        for (int nt = 0; nt < 4; ++nt) {
            short8 b = *(const short8*)&w1f[(((wv * 4 + nt) * 4 + ks) * 64 + lane) * 8];
            acc1[0][nt] = __builtin_amdgcn_mfma_f32_16x16x32_bf16(a[0][ks], b, acc1[0][nt], 0, 0, 0);
            acc1[1][nt] = __builtin_amdgcn_mfma_f32_16x16x32_bf16(a[1][ks], b, acc1[1][nt], 0, 0, 0);
        }
    }
    // relu -> bf16 -> h1S (swizzled)
#pragma unroll
    for (int mt = 0; mt < 2; ++mt)
#pragma unroll
        for (int nt = 0; nt < 4; ++nt)
#pragma unroll
            for (int i = 0; i < 4; ++i) {
                int row = mt * 16 + ((lane >> 4) << 2) + i;
                int col = (wv * 4 + nt) * 16 + (lane & 15);
                float v = fmaxf(acc1[mt][nt][i], 0.f);
                *(ushort*)&h1S[row * 512 + ((2 * col) ^ ((row & 7) << 4))] = f2bf(v);
            }
    __syncthreads();

    // ---- GEMM2: wave wv owns n-tiles [wv*2, wv*2+2) ----
    int swz = (lane & 7) << 4;
    floatx4 acc2[2][2];
#pragma unroll
    for (int nt = 0; nt < 2; ++nt) {
        float bias = b2[(wv * 2 + nt) * 16 + (lane & 15)];
#pragma unroll
        for (int mt = 0; mt < 2; ++mt)
            acc2[mt][nt] = (floatx4){bias, bias, bias, bias};
    }
#pragma unroll
    for (int ks = 0; ks < 8; ++ks) {
        int kb = ks * 64 + ((lane >> 4) << 4);
        short8 a0 = *(const short8*)&h1S[(lane & 15) * 512 + (kb ^ swz)];
        short8 a1 = *(const short8*)&h1S[(16 + (lane & 15)) * 512 + (kb ^ swz)];
#pragma unroll
        for (int nt = 0; nt < 2; ++nt) {
            short8 b = *(const short8*)&w2f[(((wv * 2 + nt) * 8 + ks) * 64 + lane) * 8];
            acc2[0][nt] = __builtin_amdgcn_mfma_f32_16x16x32_bf16(a0, b, acc2[0][nt], 0, 0, 0);
            acc2[1][nt] = __builtin_amdgcn_mfma_f32_16x16x32_bf16(a1, b, acc2[1][nt], 0, 0, 0);
        }
    }

    // ---- epilogue: bf16 store + per-column stats (fp32 pre-rounding) ----
    float s[2] = {0.f, 0.f}, s2[2] = {0.f, 0.f};
#pragma unroll
    for (int nt = 0; nt < 2; ++nt) {
        int col = (wv * 2 + nt) * 16 + (lane & 15);
#pragma unroll
        for (int mt = 0; mt < 2; ++mt)
#pragma unroll
            for (int i = 0; i < 4; ++i) {
                int row = mt * 16 + ((lane >> 4) << 2) + i;
                float v = acc2[mt][nt][i];
                hbf[(base + row) * EMB + col] = f2bf(v);
                s[nt] += v;
                s2[nt] = fmaf(v, v, s2[nt]);
            }
    }
#pragma unroll
    for (int nt = 0; nt < 2; ++nt) {
        s[nt] += __shfl_xor(s[nt], 16);
        s[nt] += __shfl_xor(s[nt], 32);
        s2[nt] += __shfl_xor(s2[nt], 16);
        s2[nt] += __shfl_xor(s2[nt], 32);
    }
    if (lane < 16) {
        float* slab = stats + (blockIdx.x & (NSLAB - 1)) * (2 * EMB);
#pragma unroll
        for (int nt = 0; nt < 2; ++nt) {
            int col = (wv * 2 + nt) * 16 + lane;
            atomicAdd(&slab[col], s[nt]);
            atomicAdd(&slab[EMB + col], s2[nt]);
        }
    }
}

// =================== fp32 MLP fallback (atomic tier only) ===================
__global__ __launch_bounds__(256) void mlp_kernel(
    float* __restrict__ h,
    const float* __restrict__ W1, const float* __restrict__ b1,
    const float* __restrict__ W2, const float* __restrict__ b2,
    float* __restrict__ stats)
{
    __shared__ float aggS[BM][EMB];
    __shared__ float h1S[BM][2 * EMB];
    __shared__ float sredS[256];
    __shared__ float s2redS[256];

    int tid = threadIdx.x;
    long base = (long)blockIdx.x * BM;

    for (int i = tid; i < BM * EMB; i += 256)
        aggS[i >> 7][i & 127] = h[base * EMB + i];
    __syncthreads();

    {
        float acc[BM];
        float bias = b1[tid];
#pragma unroll
        for (int r = 0; r < BM; ++r) acc[r] = bias;
        for (int k = 0; k < EMB; ++k) {
            float w = W1[k * (2 * EMB) + tid];
#pragma unroll
            for (int r = 0; r < BM; ++r) acc[r] = fmaf(aggS[r][k], w, acc[r]);
        }
#pragma unroll
        for (int r = 0; r < BM; ++r) h1S[r][tid] = fmaxf(acc[r], 0.0f);
    }
    __syncthreads();

    {
        int c = tid & 127;
        int half = tid >> 7;
        float acc[8];
        float bias = b2[c];
#pragma unroll
        for (int r = 0; r < 8; ++r) acc[r] = bias;
        for (int k = 0; k < 2 * EMB; ++k) {
            float w = W2[k * EMB + c];
#pragma unroll
            for (int r = 0; r < 8; ++r) acc[r] = fmaf(h1S[half * 8 + r][k], w, acc[r]);
        }
        float s = 0.f, s2 = 0.f;
#pragma unroll
        for (int r = 0; r < 8; ++r) {
            h[(base + half * 8 + r) * EMB + c] = acc[r];
            s += acc[r];
            s2 = fmaf(acc[r], acc[r], s2);
        }
        sredS[tid] = s;
        s2redS[tid] = s2;
    }
    __syncthreads();
    if (tid < 128) {
        float s = sredS[tid] + sredS[tid + 128];
        float s2 = s2redS[tid] + s2redS[tid + 128];
        float* slab = stats + (blockIdx.x & (NSLAB - 1)) * (2 * EMB);
        atomicAdd(&slab[tid], s);
        atomicAdd(&slab[EMB + tid], s2);
    }
}

// =================== BN apply: bf16 h in -> fp32 out ===============
__global__ __launch_bounds__(256) void bn_apply_bf16_kernel(
    const ushort* __restrict__ hbf, float* __restrict__ out,
    const float* __restrict__ stats,
    const float* __restrict__ gamma, const float* __restrict__ beta)
{
    __shared__ float scS[EMB], shS[EMB];
    int tid = threadIdx.x;
    if (tid < EMB) {
        float s = 0.f, s2 = 0.f;
        for (int b = 0; b < NSLAB; ++b) {
            s += stats[b * (2 * EMB) + tid];
            s2 += stats[b * (2 * EMB) + EMB + tid];
        }
        float mean = s / (float)N_NODES;
        float var = s2 / (float)N_NODES - mean * mean;
        float sc = gamma[tid] * rsqrtf(var + BN_EPS);
        scS[tid] = sc;
        shS[tid] = beta[tid] - mean * sc;
    }
    __syncthreads();
    long total = (long)N_NODES * EMB / 8;           // uint4 = 8 bf16
    long stride = (long)gridDim.x * blockDim.x;
    for (long p = (long)blockIdx.x * blockDim.x + threadIdx.x; p < total; p += stride) {
        uint4 v = ((const uint4*)hbf)[p];
        int c = (int)((p * 8) & 127);
        float4 o1, o2;
        o1.x = fmaf(lo2f(v.x), scS[c + 0], shS[c + 0]);
        o1.y = fmaf(hi2f(v.x), scS[c + 1], shS[c + 1]);
        o1.z = fmaf(lo2f(v.y), scS[c + 2], shS[c + 2]);
        o1.w = fmaf(hi2f(v.y), scS[c + 3], shS[c + 3]);
        o2.x = fmaf(lo2f(v.z), scS[c + 4], shS[c + 4]);
        o2.y = fmaf(hi2f(v.z), scS[c + 5], shS[c + 5]);
        o2.z = fmaf(lo2f(v.w), scS[c + 6], shS[c + 6]);
        o2.w = fmaf(hi2f(v.w), scS[c + 7], shS[c + 7]);
        ((float4*)out)[2 * p] = o1;
        ((float4*)out)[2 * p + 1] = o2;
    }
}

// =================== BN apply fp32 in-place (fallback tier) ===============
__global__ __launch_bounds__(256) void bn_apply_fused_kernel(
    float* __restrict__ h, const float* __restrict__ stats,
    const float* __restrict__ gamma, const float* __restrict__ beta)
{
    __shared__ float scS[EMB], shS[EMB];
    int tid = threadIdx.x;
    if (tid < EMB) {
        float s = 0.f, s2 = 0.f;
        for (int b = 0; b < NSLAB; ++b) {
            s += stats[b * (2 * EMB) + tid];
            s2 += stats[b * (2 * EMB) + EMB + tid];
        }
        float mean = s / (float)N_NODES;
        float var = s2 / (float)N_NODES - mean * mean;
        float sc = gamma[tid] * rsqrtf(var + BN_EPS);
        scS[tid] = sc;
        shS[tid] = beta[tid] - mean * sc;
    }
    __syncthreads();
    long total = (long)N_NODES * EMB / 4;
    long stride = (long)gridDim.x * blockDim.x;
    for (long i = (long)blockIdx.x * blockDim.x + threadIdx.x; i < total; i += stride) {
        float4 v = ((float4*)h)[i];
        int c = (int)((i * 4) & 127);
        v.x = fmaf(v.x, scS[c + 0], shS[c + 0]);
        v.y = fmaf(v.y, scS[c + 1], shS[c + 1]);
        v.z = fmaf(v.z, scS[c + 2], shS[c + 2]);
        v.w = fmaf(v.w, scS[c + 3], shS[c + 3]);
        ((float4*)h)[i] = v;
    }
}

extern "C" void kernel_launch(void* const* d_in, const int* in_sizes, int n_in,
                              void* d_out, int out_size, void* d_ws, size_t ws_size,
                              hipStream_t stream) {
    const float* node_feats = (const float*)d_in[0];
    const float* ef0 = (const float*)d_in[1];
    const float* ef1 = (const float*)d_in[2];
    const int* src = (const int*)d_in[3];
    const int* dst = (const int*)d_in[4];
    const float* We0 = (const float*)d_in[5];
    const float* be0 = (const float*)d_in[6];
    const float* We1 = (const float*)d_in[7];
    const float* be1 = (const float*)d_in[8];
    const float* W1 = (const float*)d_in[9];
    const float* b1 = (const float*)d_in[10];
    const float* W2 = (const float*)d_in[11];
    const float* b2 = (const float*)d_in[12];
    const float* gamma = (const float*)d_in[13];
    const float* beta = (const float*)d_in[14];

    float* out = (float*)d_out;
    ushort* aggbf = (ushort*)d_out;   // bf16 agg lives in d_out's first half

    // ws layout (65.4 MB == proven-available footprint)
    float* stats = (float*)d_ws;                          // 65536 B
    float* scaleshift = stats + NSLAB * 2 * EMB;          // 1024 B (pad)
    int* counts = (int*)(scaleshift + 256);               // NPAD ints
    int* offsets = counts + NPAD;                         // NPAD ints
    int* cursor = offsets + NPAD;                         // NPAD ints
    int* blockSums = cursor + NPAD;                       // 1024 B
    ushort* w1f = (ushort*)(blockSums + 256);             // 64 KB
    ushort* w2f = w1f + 32768;                            // 64 KB
    int* rec = (int*)(w2f + 32768);                       // E*24 B (38.4 MB)
    ushort* hbf = (ushort*)rec;                           // reuse after gather
    ushort* nfbf = (ushort*)(rec + (size_t)N_EDGES * 6);  // N*128 bf16 (25.6 MB)
    size_t needed = (size_t)((char*)(nfbf + (size_t)N_NODES * EMB) - (char*)d_ws);

    if (ws_size >= needed) {
        hipMemsetAsync(d_ws, 0,
            (size_t)(NSLAB * 2 * EMB + 256) * sizeof(float) + (size_t)NPAD * sizeof(int),
            stream);
        hist_kernel<<<(N_EDGES + 255) / 256, 256, 0, stream>>>(dst, counts);
        scan_blocksum_kernel<<<NB_SCAN, SCAN_BLK, 0, stream>>>(counts, blockSums);
        scan_final_kernel<<<NB_SCAN, SCAN_BLK, 0, stream>>>(counts, blockSums, offsets, cursor);
        scatter_fused_kernel<<<(N_EDGES + 255) / 256, 256, 0, stream>>>(
            src, dst, ef0, ef1, cursor, rec, node_feats, nfbf, W1, W2, w1f, w2f);
        gather_kernel<<<N_NODES / 8, 256, 0, stream>>>(
            nfbf, rec, offsets, We0, be0, We1, be1, aggbf);
        mlp_mfma_kernel<<<N_NODES / 32, 256, 0, stream>>>(
            aggbf, hbf, w1f, w2f, b1, b2, stats);
        bn_apply_bf16_kernel<<<1024, 256, 0, stream>>>(hbf, out, stats, gamma, beta);
    } else {
        hipMemsetAsync(stats, 0, (size_t)NSLAB * 2 * EMB * sizeof(float), stream);
        hipMemsetAsync(d_out, 0, (size_t)N_NODES * EMB * sizeof(float), stream);
        edge_scatter_kernel<<<N_EDGES / 2, 256, 0, stream>>>(
            node_feats, ef0, ef1, src, dst, We0, be0, We1, be1, out);
        mlp_kernel<<<N_NODES / BM, 256, 0, stream>>>(out, W1, b1, W2, b2, stats);
        bn_apply_fused_kernel<<<4096, 256, 0, stream>>>(out, stats, gamma, beta);
    }
}

// Round 16
// 310.705 us; speedup vs baseline: 1.4381x; 1.0640x over previous
//
#include <hip/hip_runtime.h>

#define N_NODES 100000
#define N_EDGES 1600000
#define EMB 128
#define BM 16
#define NSLAB 64
#define BN_EPS 1e-5f

#define SCAN_BLK 512
#define NB_SCAN ((N_NODES + SCAN_BLK - 1) / SCAN_BLK)   // 196
#define NPAD (NB_SCAN * SCAN_BLK)                       // 100352

typedef short short8 __attribute__((ext_vector_type(8)));
typedef float floatx4 __attribute__((ext_vector_type(4)));

__device__ __forceinline__ ushort f2bf(float x) {
    unsigned u = __float_as_uint(x);
    u += 0x7fffu + ((u >> 16) & 1u);   // RNE
    return (ushort)(u >> 16);
}
__device__ __forceinline__ float lo2f(unsigned p) {    // low bf16 of packed u32
    return __uint_as_float(p << 16);
}
__device__ __forceinline__ float hi2f(unsigned p) {    // high bf16 of packed u32
    return __uint_as_float(p & 0xffff0000u);
}

// DPP-based full-wave sum on the VALU pipe (no ds_bpermute):
#define DPP_ADD(x, ctrl, mask) \
    ((x) + __int_as_float(__builtin_amdgcn_update_dpp(0, __float_as_int(x), ctrl, mask, 0xf, true)))

__device__ __forceinline__ float wave_sum63(float x) {
    x = DPP_ADD(x, 0x111, 0xf);   // row_shr:1
    x = DPP_ADD(x, 0x112, 0xf);   // row_shr:2
    x = DPP_ADD(x, 0x114, 0xf);   // row_shr:4
    x = DPP_ADD(x, 0x118, 0xf);   // row_shr:8
    x = DPP_ADD(x, 0x142, 0xa);   // row_bcast15 -> rows 1,3
    x = DPP_ADD(x, 0x143, 0xc);   // row_bcast31 -> rows 2,3
    return __int_as_float(__builtin_amdgcn_readlane(__float_as_int(x), 63));
}

// =================== setup: nf->bf16 + dst histogram + weight frags =========
__global__ __launch_bounds__(256) void setup_kernel(
    const float* __restrict__ nf, ushort* __restrict__ nfbf,
    const int* __restrict__ dst, int* __restrict__ counts,
    const float* __restrict__ W1, const float* __restrict__ W2,
    ushort* __restrict__ w1f, ushort* __restrict__ w2f)
{
    int gtid = blockIdx.x * 256 + threadIdx.x;
    long gstride = (long)gridDim.x * 256;

    if (gtid < 65536) {
        int idx = gtid;
        int i = idx & 7;
        int lane = (idx >> 3) & 63;
        int kloc = ((lane >> 4) << 3) + i;
        int nloc = lane & 15;
        if (idx < 32768) {
            int ks = (idx >> 9) & 3, nt = idx >> 11;
            w1f[idx] = f2bf(W1[(ks * 32 + kloc) * 256 + nt * 16 + nloc]);
        } else {
            int j = idx - 32768;
            int ks = (j >> 9) & 7, nt = j >> 12;
            w2f[j] = f2bf(W2[(ks * 32 + kloc) * 128 + nt * 16 + nloc]);
        }
    }

    long total = (long)N_NODES * EMB / 4;
    for (long p = gtid; p < total; p += gstride) {
        float4 v = ((const float4*)nf)[p];
        ushort4 o;
        o.x = f2bf(v.x); o.y = f2bf(v.y); o.z = f2bf(v.z); o.w = f2bf(v.w);
        ((ushort4*)nfbf)[p] = o;
    }

    for (long e = gtid; e < N_EDGES; e += gstride)
        atomicAdd(&counts[dst[e]], 1);
}

// =================== scan machinery (2 kernels) ===================
__global__ __launch_bounds__(SCAN_BLK) void scan_blocksum_kernel(
    const int* __restrict__ counts, int* __restrict__ blockSums)
{
    __shared__ int red[SCAN_BLK];
    int t = threadIdx.x;
    int i = blockIdx.x * SCAN_BLK + t;
    red[t] = (i < N_NODES) ? counts[i] : 0;
    __syncthreads();
    for (int s = SCAN_BLK / 2; s > 0; s >>= 1) {
        if (t < s) red[t] += red[t + s];
        __syncthreads();
    }
    if (t == 0) blockSums[blockIdx.x] = red[0];
}

__global__ __launch_bounds__(SCAN_BLK) void scan_final_kernel(
    const int* __restrict__ counts, const int* __restrict__ blockSums,
    int* __restrict__ offsets, int* __restrict__ cursor)
{
    __shared__ int s[SCAN_BLK];
    __shared__ int bs[256];
    int t = threadIdx.x;
    if (t < 256) bs[t] = (t < NB_SCAN) ? blockSums[t] : 0;
    __syncthreads();
    for (int off = 1; off < 256; off <<= 1) {
        int v = (t < 256 && t >= off) ? bs[t - off] : 0;
        __syncthreads();
        if (t < 256) bs[t] += v;
        __syncthreads();
    }
    int blockBase = (blockIdx.x == 0) ? 0 : bs[blockIdx.x - 1];

    int i = blockIdx.x * SCAN_BLK + t;
    int orig = (i < N_NODES) ? counts[i] : 0;
    s[t] = orig;
    __syncthreads();
    for (int off = 1; off < SCAN_BLK; off <<= 1) {
        int v = (t >= off) ? s[t - off] : 0;
        __syncthreads();
        s[t] += v;
        __syncthreads();
    }
    int excl = s[t] - orig + blockBase;
    if (i < N_NODES) { offsets[i] = excl; cursor[i] = excl; }
    if (i == N_NODES) offsets[N_NODES] = N_EDGES;
}

// =================== scatter: 24B records {src, 9xbf16} sorted by dst =======
__global__ __launch_bounds__(256) void scatter24_kernel(
    const int* __restrict__ src, const int* __restrict__ dst,
    const float* __restrict__ ef0, const float* __restrict__ ef1,
    int* __restrict__ cursor, int* __restrict__ rec)
{
    int e = blockIdx.x * 256 + threadIdx.x;
    if (e >= N_EDGES) return;
    int t = dst[e];
    int pos = atomicAdd(&cursor[t], 1);

    const float2* p0 = (const float2*)(ef0 + (long)e * 6);
    float2 q0 = p0[0], q1 = p0[1], q2 = p0[2];
    const float* p1 = ef1 + (long)e * 3;
    float g0 = p1[0], g1 = p1[1], g2 = p1[2];

    int u0 = (int)((unsigned)f2bf(q0.x) | ((unsigned)f2bf(q0.y) << 16));
    int u1 = (int)((unsigned)f2bf(q1.x) | ((unsigned)f2bf(q1.y) << 16));
    int u2 = (int)((unsigned)f2bf(q2.x) | ((unsigned)f2bf(q2.y) << 16));
    int u3 = (int)((unsigned)f2bf(g0)   | ((unsigned)f2bf(g1) << 16));
    int u4 = (int)((unsigned)f2bf(g2));

    int2* out = (int2*)(rec + (long)pos * 6);
    out[0] = make_int2(src[e], u0);
    out[1] = make_int2(u1, u2);
    out[2] = make_int2(u3, u4);
}

// per-record read: returns src id, accumulates 9 features (24B records)
__device__ __forceinline__ int read_rec(const int* __restrict__ rec, long pos,
                                        float* fs) {
    const int* p = rec + pos * 6;
    int2 a = ((const int2*)p)[0], b = ((const int2*)p)[1], c = ((const int2*)p)[2];
    unsigned w1 = (unsigned)a.y, w2 = (unsigned)b.x, w3 = (unsigned)b.y;
    unsigned w4 = (unsigned)c.x, w5 = (unsigned)c.y;
    fs[0] += lo2f(w1); fs[1] += hi2f(w1);
    fs[2] += lo2f(w2); fs[3] += hi2f(w2);
    fs[4] += lo2f(w3); fs[5] += hi2f(w3);
    fs[6] += lo2f(w4); fs[7] += hi2f(w4);
    fs[8] += lo2f(w5);
    return a.x;
}

// full-chunk helper (deg >= 64 segments)
__device__ __forceinline__ void gather_full_chunks(
    int& base, int end, int lane, int q, int lp,
    const int* __restrict__ rec, const int4* __restrict__ nf16,
    float4& accA, float4& accB, float* fs)
{
    for (; base + 64 <= end; base += 64) {
        int sid = read_rec(rec, (long)(base + lane), fs);
#pragma unroll 4
        for (int j = 0; j < 16; ++j) {
            int s = __shfl(sid, 4 * j + q);
            int4 nv = nf16[(long)s * 16 + lp];
            accA.x += lo2f((unsigned)nv.x); accA.y += hi2f((unsigned)nv.x);
            accA.z += lo2f((unsigned)nv.y); accA.w += hi2f((unsigned)nv.y);
            accB.x += lo2f((unsigned)nv.z); accB.y += hi2f((unsigned)nv.z);
            accB.z += lo2f((unsigned)nv.w); accB.w += hi2f((unsigned)nv.w);
        }
    }
}

// =================== gather: 2 nodes/wave, 8 rows in flight, bf16 agg out ===
__global__ __launch_bounds__(256, 8) void gather_kernel(
    const ushort* __restrict__ nfbf, const int* __restrict__ rec,
    const int* __restrict__ offsets,
    const float* __restrict__ We0, const float* __restrict__ be0,
    const float* __restrict__ We1, const float* __restrict__ be1,
    ushort* __restrict__ aggbf)
{
    int wv = threadIdx.x >> 6, lane = threadIdx.x & 63;
    int n0 = blockIdx.x * 8 + wv * 2;          // N_NODES % 8 == 0
    int q = lane >> 4, lp = lane & 15;
    const int4* nf16 = (const int4*)nfbf;      // row = 16 int4

    int beg0 = offsets[n0];
    int mid  = offsets[n0 + 1];
    int end1 = offsets[n0 + 2];

    float4 a0A = make_float4(0.f, 0.f, 0.f, 0.f), a0B = a0A;
    float4 a1A = a0A, a1B = a0A;
    float fs0[9] = {}, fs1[9] = {};

    int b0 = beg0, b1 = mid;
    gather_full_chunks(b0, mid, lane, q, lp, rec, nf16, a0A, a0B, fs0);
    gather_full_chunks(b1, end1, lane, q, lp, rec, nf16, a1A, a1B, fs1);

    // interleaved tails
    int m0 = mid - b0, m1 = end1 - b1;
    int sid0 = 0, sid1 = 0;
    if (lane < m0) sid0 = read_rec(rec, (long)(b0 + lane), fs0);
    if (lane < m1) sid1 = read_rec(rec, (long)(b1 + lane), fs1);

    int mx = m0 > m1 ? m0 : m1;
    int rounds = (mx + 3) >> 2;
#pragma unroll 4
    for (int j = 0; j < rounds; ++j) {
        int r = 4 * j + q;
        int s0 = __shfl(sid0, r);
        int s1 = __shfl(sid1, r);
        if (r < m0) {
            int4 nv = nf16[(long)s0 * 16 + lp];
            a0A.x += lo2f((unsigned)nv.x); a0A.y += hi2f((unsigned)nv.x);
            a0A.z += lo2f((unsigned)nv.y); a0A.w += hi2f((unsigned)nv.y);
            a0B.x += lo2f((unsigned)nv.z); a0B.y += hi2f((unsigned)nv.z);
            a0B.z += lo2f((unsigned)nv.w); a0B.w += hi2f((unsigned)nv.w);
        }
        if (r < m1) {
            int4 nv = nf16[(long)s1 * 16 + lp];
            a1A.x += lo2f((unsigned)nv.x); a1A.y += hi2f((unsigned)nv.x);
            a1A.z += lo2f((unsigned)nv.y); a1A.w += hi2f((unsigned)nv.y);
            a1B.x += lo2f((unsigned)nv.z); a1B.y += hi2f((unsigned)nv.z);
            a1B.z += lo2f((unsigned)nv.w); a1B.w += hi2f((unsigned)nv.w);
        }
    }

    // cross-quarter reductions -> values uniform across quarters at fixed lp
#define QRED(v) v += __shfl_xor(v, 16); v += __shfl_xor(v, 32);
    QRED(a0A.x) QRED(a0A.y) QRED(a0A.z) QRED(a0A.w)
    QRED(a0B.x) QRED(a0B.y) QRED(a0B.z) QRED(a0B.w)
    QRED(a1A.x) QRED(a1A.y) QRED(a1A.z) QRED(a1A.w)
    QRED(a1B.x) QRED(a1B.y) QRED(a1B.z) QRED(a1B.w)
#undef QRED

    // feature sums on the VALU pipe
    float fk0[9], fk1[9];
#pragma unroll
    for (int k = 0; k < 9; ++k) {
        fk0[k] = wave_sum63(fs0[k]);
        fk1[k] = wave_sum63(fs1[k]);
    }

    // epilogue over all 4 quarters: node = q&1, dim-half = q>>1
    int nodesel = q & 1;
    int hh = q >> 1;
    long myn = (long)n0 + nodesel;
    float deg = nodesel ? (float)(end1 - mid) : (float)(mid - beg0);
    float4 acc;
    {
        float4 selA, selB;
        selA.x = nodesel ? a1A.x : a0A.x; selA.y = nodesel ? a1A.y : a0A.y;
        selA.z = nodesel ? a1A.z : a0A.z; selA.w = nodesel ? a1A.w : a0A.w;
        selB.x = nodesel ? a1B.x : a0B.x; selB.y = nodesel ? a1B.y : a0B.y;
        selB.z = nodesel ? a1B.z : a0B.z; selB.w = nodesel ? a1B.w : a0B.w;
        acc.x = hh ? selB.x : selA.x; acc.y = hh ? selB.y : selA.y;
        acc.z = hh ? selB.z : selA.z; acc.w = hh ? selB.w : selA.w;
    }
    int fidx = 2 * lp + hh;
    float4 bb0 = ((const float4*)be0)[fidx];
    float4 bb1 = ((const float4*)be1)[fidx];
    float4 e;
    e.x = deg * (bb0.x + bb1.x); e.y = deg * (bb0.y + bb1.y);
    e.z = deg * (bb0.z + bb1.z); e.w = deg * (bb0.w + bb1.w);
#pragma unroll
    for (int k = 0; k < 6; ++k) {
        float f = nodesel ? fk1[k] : fk0[k];
        float4 w = ((const float4*)We0)[k * 32 + fidx];
        e.x = fmaf(f, w.x, e.x); e.y = fmaf(f, w.y, e.y);
        e.z = fmaf(f, w.z, e.z); e.w = fmaf(f, w.w, e.w);
    }
#pragma unroll
    for (int k = 0; k < 3; ++k) {
        float f = nodesel ? fk1[6 + k] : fk0[6 + k];
        float4 w = ((const float4*)We1)[k * 32 + fidx];
        e.x = fmaf(f, w.x, e.x); e.y = fmaf(f, w.y, e.y);
        e.z = fmaf(f, w.z, e.z); e.w = fmaf(f, w.w, e.w);
    }
    ushort4 o;
    o.x = f2bf(acc.x + e.x); o.y = f2bf(acc.y + e.y);
    o.z = f2bf(acc.z + e.z); o.w = f2bf(acc.w + e.w);
    ((ushort4*)aggbf)[myn * 32 + fidx] = o;
}

// =================== LAST resort: atomic path ===================
__global__ __launch_bounds__(256) void edge_scatter_kernel(
    const float* __restrict__ node_feats,
    const float* __restrict__ ef0,
    const float* __restrict__ ef1,
    const int* __restrict__ src,
    const int* __restrict__ dst,
    const float* __restrict__ We0, const float* __restrict__ be0,
    const float* __restrict__ We1, const float* __restrict__ be1,
    float* __restrict__ agg)
{
    __shared__ float wS[10 * EMB];
    int tid = threadIdx.x;
    for (int i = tid; i < 6 * EMB; i += 256) wS[i] = We0[i];
    for (int i = tid; i < 3 * EMB; i += 256) wS[6 * EMB + i] = We1[i];
    if (tid < EMB) wS[9 * EMB + tid] = be0[tid] + be1[tid];
    __syncthreads();

    int e = blockIdx.x * 2 + (tid >> 7);
    if (e >= N_EDGES) return;
    int d = tid & 127;
    int s = src[e];
    int t = dst[e];
    const float* f0 = ef0 + (long)e * 6;
    const float* f1 = ef1 + (long)e * 3;

    float emb = wS[9 * EMB + d];
#pragma unroll
    for (int k = 0; k < 6; ++k) emb = fmaf(f0[k], wS[k * EMB + d], emb);
#pragma unroll
    for (int k = 0; k < 3; ++k) emb = fmaf(f1[k], wS[6 * EMB + k * EMB + d], emb);

    float val = node_feats[(long)s * EMB + d] + emb;
    atomicAdd(&agg[(long)t * EMB + d], val);
}

// =============== fused MFMA MLP + BN stats (A bf16 in, h bf16 out) ==========
__global__ __launch_bounds__(256) void mlp_mfma_kernel(
    const ushort* __restrict__ aggbf, ushort* __restrict__ hbf,
    const ushort* __restrict__ w1f, const ushort* __restrict__ w2f,
    const float* __restrict__ b1, const float* __restrict__ b2,
    float* __restrict__ stats)
{
    __shared__ __align__(16) char h1S[32 * 512];    // 32 rows x 256 bf16, swizzled

    int tid = threadIdx.x;
    int lane = tid & 63;
    int wv = tid >> 6;
    long base = (long)blockIdx.x * 32;

    // ---- A fragments straight from global bf16 agg ----
    short8 a[2][4];
#pragma unroll
    for (int mt = 0; mt < 2; ++mt)
#pragma unroll
        for (int ks = 0; ks < 4; ++ks) {
            long row = base + mt * 16 + (lane & 15);
            a[mt][ks] = *(const short8*)&aggbf[row * EMB + ks * 32 + ((lane >> 4) << 3)];
        }

    // ---- GEMM1: wave wv owns n-tiles [wv*4, wv*4+4) ----
    floatx4 acc1[2][4];
#pragma unroll
    for (int nt = 0; nt < 4; ++nt) {
        float bias = b1[(wv * 4 + nt) * 16 + (lane & 15)];
#pragma unroll
        for (int mt = 0; mt < 2; ++mt)
            acc1[mt][nt] = (floatx4){bias, bias, bias, bias};
    }
#pragma unroll
    for (int ks = 0; ks < 4; ++ks) {
#pragma unroll
        for (int nt = 0; nt < 4; ++nt) {
            short8 b = *(const short8*)&w1f[(((wv * 4 + nt) * 4 + ks) * 64 + lane) * 8];
            acc1[0][nt] = __builtin_amdgcn_mfma_f32_16x16x32_bf16(a[0][ks], b, acc1[0][nt], 0, 0, 0);
            acc1[1][nt] = __builtin_amdgcn_mfma_f32_16x16x32_bf16(a[1][ks], b, acc1[1][nt], 0, 0, 0);
        }
    }
    // relu -> bf16 -> h1S (swizzled)
#pragma unroll
    for (int mt = 0; mt < 2; ++mt)
#pragma unroll
        for (int nt = 0; nt < 4; ++nt)
#pragma unroll
            for (int i = 0; i < 4; ++i) {
                int row = mt * 16 + ((lane >> 4) << 2) + i;
                int col = (wv * 4 + nt) * 16 + (lane & 15);
                float v = fmaxf(acc1[mt][nt][i], 0.f);
                *(ushort*)&h1S[row * 512 + ((2 * col) ^ ((row & 7) << 4))] = f2bf(v);
            }
    __syncthreads();

    // ---- GEMM2: wave wv owns n-tiles [wv*2, wv*2+2) ----
    int swz = (lane & 7) << 4;
    floatx4 acc2[2][2];
#pragma unroll
    for (int nt = 0; nt < 2; ++nt) {
        float bias = b2[(wv * 2 + nt) * 16 + (lane & 15)];
#pragma unroll
        for (int mt = 0; mt < 2; ++mt)
            acc2[mt][nt] = (floatx4){bias, bias, bias, bias};
    }
#pragma unroll
    for (int ks = 0; ks < 8; ++ks) {
        int kb = ks * 64 + ((lane >> 4) << 4);
        short8 a0 = *(const short8*)&h1S[(lane & 15) * 512 + (kb ^ swz)];
        short8 a1 = *(const short8*)&h1S[(16 + (lane & 15)) * 512 + (kb ^ swz)];
#pragma unroll
        for (int nt = 0; nt < 2; ++nt) {
            short8 b = *(const short8*)&w2f[(((wv * 2 + nt) * 8 + ks) * 64 + lane) * 8];
            acc2[0][nt] = __builtin_amdgcn_mfma_f32_16x16x32_bf16(a0, b, acc2[0][nt], 0, 0, 0);
            acc2[1][nt] = __builtin_amdgcn_mfma_f32_16x16x32_bf16(a1, b, acc2[1][nt], 0, 0, 0);
        }
    }

    // ---- epilogue: bf16 store + per-column stats (fp32 pre-rounding) ----
    float s[2] = {0.f, 0.f}, s2[2] = {0.f, 0.f};
#pragma unroll
    for (int nt = 0; nt < 2; ++nt) {
        int col = (wv * 2 + nt) * 16 + (lane & 15);
#pragma unroll
        for (int mt = 0; mt < 2; ++mt)
#pragma unroll
            for (int i = 0; i < 4; ++i) {
                int row = mt * 16 + ((lane >> 4) << 2) + i;
                float v = acc2[mt][nt][i];
                hbf[(base + row) * EMB + col] = f2bf(v);
                s[nt] += v;
                s2[nt] = fmaf(v, v, s2[nt]);
            }
    }
#pragma unroll
    for (int nt = 0; nt < 2; ++nt) {
        s[nt] += __shfl_xor(s[nt], 16);
        s[nt] += __shfl_xor(s[nt], 32);
        s2[nt] += __shfl_xor(s2[nt], 16);
        s2[nt] += __shfl_xor(s2[nt], 32);
    }
    if (lane < 16) {
        float* slab = stats + (blockIdx.x & (NSLAB - 1)) * (2 * EMB);
#pragma unroll
        for (int nt = 0; nt < 2; ++nt) {
            int col = (wv * 2 + nt) * 16 + lane;
            atomicAdd(&slab[col], s[nt]);
            atomicAdd(&slab[EMB + col], s2[nt]);
        }
    }
}

// =================== fp32 MLP fallback (atomic tier only) ===================
__global__ __launch_bounds__(256) void mlp_kernel(
    float* __restrict__ h,
    const float* __restrict__ W1, const float* __restrict__ b1,
    const float* __restrict__ W2, const float* __restrict__ b2,
    float* __restrict__ stats)
{
    __shared__ float aggS[BM][EMB];
    __shared__ float h1S[BM][2 * EMB];
    __shared__ float sredS[256];
    __shared__ float s2redS[256];

    int tid = threadIdx.x;
    long base = (long)blockIdx.x * BM;

    for (int i = tid; i < BM * EMB; i += 256)
        aggS[i >> 7][i & 127] = h[base * EMB + i];
    __syncthreads();

    {
        float acc[BM];
        float bias = b1[tid];
#pragma unroll
        for (int r = 0; r < BM; ++r) acc[r] = bias;
        for (int k = 0; k < EMB; ++k) {
            float w = W1[k * (2 * EMB) + tid];
#pragma unroll
            for (int r = 0; r < BM; ++r) acc[r] = fmaf(aggS[r][k], w, acc[r]);
        }
#pragma unroll
        for (int r = 0; r < BM; ++r) h1S[r][tid] = fmaxf(acc[r], 0.0f);
    }
    __syncthreads();

    {
        int c = tid & 127;
        int half = tid >> 7;
        float acc[8];
        float bias = b2[c];
#pragma unroll
        for (int r = 0; r < 8; ++r) acc[r] = bias;
        for (int k = 0; k < 2 * EMB; ++k) {
            float w = W2[k * EMB + c];
#pragma unroll
            for (int r = 0; r < 8; ++r) acc[r] = fmaf(h1S[half * 8 + r][k], w, acc[r]);
        }
        float s = 0.f, s2 = 0.f;
#pragma unroll
        for (int r = 0; r < 8; ++r) {
            h[(base + half * 8 + r) * EMB + c] = acc[r];
            s += acc[r];
            s2 = fmaf(acc[r], acc[r], s2);
        }
        sredS[tid] = s;
        s2redS[tid] = s2;
    }
    __syncthreads();
    if (tid < 128) {
        float s = sredS[tid] + sredS[tid + 128];
        float s2 = s2redS[tid] + s2redS[tid + 128];
        float* slab = stats + (blockIdx.x & (NSLAB - 1)) * (2 * EMB);
        atomicAdd(&slab[tid], s);
        atomicAdd(&slab[EMB + tid], s2);
    }
}

// =================== BN apply: bf16 h in -> fp32 out ===============
__global__ __launch_bounds__(256) void bn_apply_bf16_kernel(
    const ushort* __restrict__ hbf, float* __restrict__ out,
    const float* __restrict__ stats,
    const float* __restrict__ gamma, const float* __restrict__ beta)
{
    __shared__ float scS[EMB], shS[EMB];
    int tid = threadIdx.x;
    if (tid < EMB) {
        float s = 0.f, s2 = 0.f;
        for (int b = 0; b < NSLAB; ++b) {
            s += stats[b * (2 * EMB) + tid];
            s2 += stats[b * (2 * EMB) + EMB + tid];
        }
        float mean = s / (float)N_NODES;
        float var = s2 / (float)N_NODES - mean * mean;
        float sc = gamma[tid] * rsqrtf(var + BN_EPS);
        scS[tid] = sc;
        shS[tid] = beta[tid] - mean * sc;
    }
    __syncthreads();
    long total = (long)N_NODES * EMB / 8;           // uint4 = 8 bf16
    long stride = (long)gridDim.x * blockDim.x;
    for (long p = (long)blockIdx.x * blockDim.x + threadIdx.x; p < total; p += stride) {
        uint4 v = ((const uint4*)hbf)[p];
        int c = (int)((p * 8) & 127);
        float4 o1, o2;
        o1.x = fmaf(lo2f(v.x), scS[c + 0], shS[c + 0]);
        o1.y = fmaf(hi2f(v.x), scS[c + 1], shS[c + 1]);
        o1.z = fmaf(lo2f(v.y), scS[c + 2], shS[c + 2]);
        o1.w = fmaf(hi2f(v.y), scS[c + 3], shS[c + 3]);
        o2.x = fmaf(lo2f(v.z), scS[c + 4], shS[c + 4]);
        o2.y = fmaf(hi2f(v.z), scS[c + 5], shS[c + 5]);
        o2.z = fmaf(lo2f(v.w), scS[c + 6], shS[c + 6]);
        o2.w = fmaf(hi2f(v.w), scS[c + 7], shS[c + 7]);
        ((float4*)out)[2 * p] = o1;
        ((float4*)out)[2 * p + 1] = o2;
    }
}

// =================== BN apply fp32 in-place (fallback tier) ===============
__global__ __launch_bounds__(256) void bn_apply_fused_kernel(
    float* __restrict__ h, const float* __restrict__ stats,
    const float* __restrict__ gamma, const float* __restrict__ beta)
{
    __shared__ float scS[EMB], shS[EMB];
    int tid = threadIdx.x;
    if (tid < EMB) {
        float s = 0.f, s2 = 0.f;
        for (int b = 0; b < NSLAB; ++b) {
            s += stats[b * (2 * EMB) + tid];
            s2 += stats[b * (2 * EMB) + EMB + tid];
        }
        float mean = s / (float)N_NODES;
        float var = s2 / (float)N_NODES - mean * mean;
        float sc = gamma[tid] * rsqrtf(var + BN_EPS);
        scS[tid] = sc;
        shS[tid] = beta[tid] - mean * sc;
    }
    __syncthreads();
    long total = (long)N_NODES * EMB / 4;
    long stride = (long)gridDim.x * blockDim.x;
    for (long i = (long)blockIdx.x * blockDim.x + threadIdx.x; i < total; i += stride) {
        float4 v = ((float4*)h)[i];
        int c = (int)((i * 4) & 127);
        v.x = fmaf(v.x, scS[c + 0], shS[c + 0]);
        v.y = fmaf(v.y, scS[c + 1], shS[c + 1]);
        v.z = fmaf(v.z, scS[c + 2], shS[c + 2]);
        v.w = fmaf(v.w, scS[c + 3], shS[c + 3]);
        ((float4*)h)[i] = v;
    }
}

extern "C" void kernel_launch(void* const* d_in, const int* in_sizes, int n_in,
                              void* d_out, int out_size, void* d_ws, size_t ws_size,
                              hipStream_t stream) {
    const float* node_feats = (const float*)d_in[0];
    const float* ef0 = (const float*)d_in[1];
    const float* ef1 = (const float*)d_in[2];
    const int* src = (const int*)d_in[3];
    const int* dst = (const int*)d_in[4];
    const float* We0 = (const float*)d_in[5];
    const float* be0 = (const float*)d_in[6];
    const float* We1 = (const float*)d_in[7];
    const float* be1 = (const float*)d_in[8];
    const float* W1 = (const float*)d_in[9];
    const float* b1 = (const float*)d_in[10];
    const float* W2 = (const float*)d_in[11];
    const float* b2 = (const float*)d_in[12];
    const float* gamma = (const float*)d_in[13];
    const float* beta = (const float*)d_in[14];

    float* out = (float*)d_out;
    ushort* aggbf = (ushort*)d_out;   // bf16 agg lives in d_out's first half

    // ws layout (65.4 MB == proven-available footprint)
    float* stats = (float*)d_ws;                          // 65536 B
    float* scaleshift = stats + NSLAB * 2 * EMB;          // 1024 B (pad)
    int* counts = (int*)(scaleshift + 256);               // NPAD ints
    int* offsets = counts + NPAD;                         // NPAD ints
    int* cursor = offsets + NPAD;                         // NPAD ints
    int* blockSums = cursor + NPAD;                       // 1024 B
    ushort* w1f = (ushort*)(blockSums + 256);             // 64 KB
    ushort* w2f = w1f + 32768;                            // 64 KB
    int* rec = (int*)(w2f + 32768);                       // E*24 B (38.4 MB)
    ushort* hbf = (ushort*)rec;                           // reuse after gather
    ushort* nfbf = (ushort*)(rec + (size_t)N_EDGES * 6);  // N*128 bf16 (25.6 MB)
    size_t needed = (size_t)((char*)(nfbf + (size_t)N_NODES * EMB) - (char*)d_ws);

    if (ws_size >= needed) {
        hipMemsetAsync(d_ws, 0,
            (size_t)(NSLAB * 2 * EMB + 256) * sizeof(float) + (size_t)NPAD * sizeof(int),
            stream);
        setup_kernel<<<2048, 256, 0, stream>>>(
            node_feats, nfbf, dst, counts, W1, W2, w1f, w2f);
        scan_blocksum_kernel<<<NB_SCAN, SCAN_BLK, 0, stream>>>(counts, blockSums);
        scan_final_kernel<<<NB_SCAN, SCAN_BLK, 0, stream>>>(counts, blockSums, offsets, cursor);
        scatter24_kernel<<<(N_EDGES + 255) / 256, 256, 0, stream>>>(
            src, dst, ef0, ef1, cursor, rec);
        gather_kernel<<<N_NODES / 8, 256, 0, stream>>>(
            nfbf, rec, offsets, We0, be0, We1, be1, aggbf);
        mlp_mfma_kernel<<<N_NODES / 32, 256, 0, stream>>>(
            aggbf, hbf, w1f, w2f, b1, b2, stats);
        bn_apply_bf16_kernel<<<1024, 256, 0, stream>>>(hbf, out, stats, gamma, beta);
    } else {
        hipMemsetAsync(stats, 0, (size_t)NSLAB * 2 * EMB * sizeof(float), stream);
        hipMemsetAsync(d_out, 0, (size_t)N_NODES * EMB * sizeof(float), stream);
        edge_scatter_kernel<<<N_EDGES / 2, 256, 0, stream>>>(
            node_feats, ef0, ef1, src, dst, We0, be0, We1, be1, out);
        mlp_kernel<<<N_NODES / BM, 256, 0, stream>>>(out, W1, b1, W2, b2, stats);
        bn_apply_fused_kernel<<<4096, 256, 0, stream>>>(out, stats, gamma, beta);
    }
}